// Round 7
// baseline (499.207 us; speedup 1.0000x reference)
//
#include <hip/hip_runtime.h>
#include <cstdint>
#include <cstddef>

#define Bsz 8
#define Ssz 256
#define Msz 2048
#define SPLITK 16
#define NBLK 512

typedef _Float16 f16x8 __attribute__((ext_vector_type(8)));
typedef float f32x16 __attribute__((ext_vector_type(16)));

// ---- device-scope grid barrier (normal launch; co-residency by resource math:
// launch_bounds(256,2) -> 2 blocks/CU x 256 CU = 512 = grid). Zero-init device
// globals; g_cnt self-restores to 0, g_gen monotonic -> replay-safe, no init pass.
__device__ unsigned g_cnt = 0;
__device__ unsigned g_gen = 0;

__device__ __forceinline__ void grid_barrier() {
  __syncthreads();
  if (threadIdx.x == 0) {
    __threadfence();                                   // release: block's writes -> device
    unsigned g = __atomic_load_n(&g_gen, __ATOMIC_ACQUIRE);   // read gen BEFORE arrive
    unsigned old = atomicAdd(&g_cnt, 1u);              // device-scope RMW
    if (old == NBLK - 1) {
      __atomic_store_n(&g_cnt, 0u, __ATOMIC_RELAXED);
      __threadfence();
      __atomic_store_n(&g_gen, g + 1u, __ATOMIC_RELEASE);
    } else {
      while (__atomic_load_n(&g_gen, __ATOMIC_ACQUIRE) == g)
        __builtin_amdgcn_s_sleep(2);
    }
    __threadfence();                                   // acquire: see other blocks' writes
  }
  __syncthreads();
}

// ---- GEMM stage: 64m x 128n tile, 4 waves, A hoisted, XCD-aware (mb,sk) ----
// mfma_f32_32x32x16_f16: A row=lane&31, k=(lane>>5)*8+j; B col same; D col=lane&31,
// row=(reg&3)+8*(reg>>2)+4*(lane>>5).
template<int LGDV, int KC>
__device__ __forceinline__ void gemm_stage(
    const _Float16* __restrict__ Apk,   // [DV/8][Msz][8]
    const _Float16* __restrict__ Wpk,   // [Ktot/16][4][64][8]
    const _Float16* __restrict__ tokT,  // [128][Msz]
    float* __restrict__ part)           // [SPLITK][Msz][128]
{
  constexpr int DV  = 1 << LGDV;
  constexpr int NT  = KC >> LGDV;      // 8
  constexpr int NKS = DV >> 4;         // 4 or 8

  const int tid  = threadIdx.x;
  const int lane = tid & 63;
  const int wo   = tid >> 6;
  const int l31  = lane & 31;
  const int lg   = lane >> 5;
  const int id   = blockIdx.x;
  const int sk   = ((id & 7) << 1) | (id >> 8);   // same-XCD blocks share sk -> W in L2
  const int mb   = (id >> 3) & 31;
  const int m0   = mb * 64;
  const int mrow0 = m0 + l31;

  f16x8 a0[NKS], a1[NKS];
  #pragma unroll
  for (int ks = 0; ks < NKS; ++ks) {
    const _Float16* ap = Apk + ((size_t)(ks * 2 + lg) * Msz + mrow0) * 8;
    a0[ks] = *(const f16x8*)(ap);
    a1[ks] = *(const f16x8*)(ap + 32 * 8);
  }

  f32x16 acc0 = {}, acc1 = {};
  const int t0 = sk * NT;

  #pragma unroll 1
  for (int tg = 0; tg < NT; ++tg) {
    const int t = t0 + tg;
    const _Float16 ta = tokT[(size_t)t * Msz + mrow0];
    const _Float16 tb = tokT[(size_t)t * Msz + mrow0 + 32];
    const f16x8 tav = {ta,ta,ta,ta,ta,ta,ta,ta};
    const f16x8 tbv = {tb,tb,tb,tb,tb,tb,tb,tb};
    const int kcBase = sk * (KC >> 4) + tg * NKS;
    #pragma unroll
    for (int ks = 0; ks < NKS; ++ks) {
      const f16x8 b = *(const f16x8*)(Wpk + (((size_t)(kcBase + ks) * 4 + wo) * 64 + lane) * 8);
      const f16x8 af0 = tav * a0[ks];
      const f16x8 af1 = tbv * a1[ks];
      acc0 = __builtin_amdgcn_mfma_f32_32x32x16_f16(af0, b, acc0, 0, 0, 0);
      acc1 = __builtin_amdgcn_mfma_f32_32x32x16_f16(af1, b, acc1, 0, 0, 0);
    }
  }

  float* dst = part + (size_t)sk * Msz * 128;
  const int ocol = wo * 32 + l31;
  #pragma unroll
  for (int r = 0; r < 16; ++r) {
    const int mrow = m0 + (r & 3) + 8 * (r >> 2) + 4 * lg;
    dst[(size_t)mrow * 128 + ocol]        = acc0[r];
    dst[(size_t)(mrow + 32) * 128 + ocol] = acc1[r];
  }
}

// ---- split-K reduce + bias + tanh ----
template<bool TO_HPK>
__device__ __forceinline__ void red_stage(
    const float* __restrict__ part, const float* __restrict__ bias,
    _Float16* __restrict__ hpk, float* __restrict__ spc)
{
  const int tg0 = blockIdx.x * 256 + threadIdx.x;   // 131072 threads, 262144 elems
  #pragma unroll
  for (int r = 0; r < 2; ++r) {
    const int e = tg0 + r * (NBLK * 256);
    const int m = e >> 7, p = e & 127;
    float s = bias[p];
    #pragma unroll
    for (int sk = 0; sk < SPLITK; sk++) s += part[(size_t)sk * (Msz * 128) + e];
    const float v = tanhf(s);
    if (TO_HPK) hpk[((size_t)(p >> 3) * Msz + m) * 8 + (p & 7)] = (_Float16)v;
    else        spc[e] = v;
  }
}

// ---- fused megakernel ----
__global__ __launch_bounds__(256, 2) void k_mega(
    const float* __restrict__ tok,  const float* __restrict__ dep,
    const int*   __restrict__ hds,  const float* __restrict__ W1,
    const float* __restrict__ bdep, const float* __restrict__ W2,
    const float* __restrict__ bcomp,const float* __restrict__ wred,
    const float* __restrict__ bred, float* __restrict__ out,
    _Float16* __restrict__ W1pk, _Float16* __restrict__ W2pk,
    _Float16* __restrict__ dpk,  _Float16* __restrict__ tokT,
    _Float16* __restrict__ hpk,  float* __restrict__ part,
    float* __restrict__ spc)
{
  __shared__ float tile[32][33];
  __shared__ float wr_s[Ssz];
  __shared__ int   hd_s[Ssz];
  __shared__ float cAcc[2][128];
  __shared__ float cSwr[2][128];

  const int tid = threadIdx.x;

  // ---------- S0: pack (grid-stride over 1088 units) ----------
  for (int u = blockIdx.x; u < 1088; u += NBLK) {
    if (u < 768) {             // W1 (u<256) or W2 -> [kc][4][64][8] f16
      const bool isW1 = u < 256;
      const int idx = (isW1 ? u : u - 256) * 256 + tid;
      const int r  = idx & 31;
      const int pb = (idx >> 5) & 3;
      const int kc = idx >> 7;
      const float* src = (isW1 ? W1 : W2) + (size_t)(pb * 32 + r) * (isW1 ? 8192 : 16384) + kc * 16;
      const float4* s4 = (const float4*)src;
      float4 u0 = s4[0], u1 = s4[1], u2 = s4[2], u3 = s4[3];
      f16x8 lo = {(_Float16)u0.x,(_Float16)u0.y,(_Float16)u0.z,(_Float16)u0.w,
                  (_Float16)u1.x,(_Float16)u1.y,(_Float16)u1.z,(_Float16)u1.w};
      f16x8 hi = {(_Float16)u2.x,(_Float16)u2.y,(_Float16)u2.z,(_Float16)u2.w,
                  (_Float16)u3.x,(_Float16)u3.y,(_Float16)u3.z,(_Float16)u3.w};
      _Float16* dst = (isW1 ? W1pk : W2pk) + ((size_t)(kc * 4 + pb) * 64) * 8;
      *(f16x8*)(dst + (size_t)r * 8)        = lo;
      *(f16x8*)(dst + (size_t)(32 + r) * 8) = hi;
    } else if (u < 832) {      // dep -> dpk [8][2048][8]
      const int idx = (u - 768) * 256 + tid;
      const int m = idx & 2047, pc = idx >> 11;
      const float4* s4 = (const float4*)(dep + (size_t)m * 64 + pc * 8);
      float4 u0 = s4[0], u1 = s4[1];
      f16x8 v = {(_Float16)u0.x,(_Float16)u0.y,(_Float16)u0.z,(_Float16)u0.w,
                 (_Float16)u1.x,(_Float16)u1.y,(_Float16)u1.z,(_Float16)u1.w};
      *(f16x8*)(dpk + ((size_t)pc * Msz + m) * 8) = v;
    } else {                   // tok -> tokT [128][2048] f16 (32x32 LDS tiles)
      const int q = u - 832;
      const int mt = q >> 2, tt = q & 3;
      const int tx = tid & 31, ty = tid >> 5;
      __syncthreads();
      for (int yy = ty; yy < 32; yy += 8)
        tile[yy][tx] = tok[(size_t)(mt * 32 + yy) * 128 + tt * 32 + tx];
      __syncthreads();
      for (int yy = ty; yy < 32; yy += 8)
        tokT[(size_t)(tt * 32 + yy) * Msz + mt * 32 + tx] = (_Float16)tile[tx][yy];
    }
  }
  grid_barrier();

  // ---------- S1: phase-1 GEMM (K=8192, Dv=64) ----------
  gemm_stage<6, 512>(dpk, W1pk, tokT, part);
  grid_barrier();

  // ---------- S2: reduce + tanh -> hpk ----------
  red_stage<true>(part, bdep, hpk, nullptr);
  grid_barrier();

  // ---------- S3: phase-2 GEMM (K=16384, Dv=128) ----------
  gemm_stage<7, 1024>(hpk, W2pk, tokT, part);
  grid_barrier();

  // ---------- S4: reduce + tanh -> spc ----------
  red_stage<false>(part, bcomp, nullptr, spc);
  grid_barrier();

  // ---------- S5: finalize (gather j with head==i), 4 units/block ----------
  const int bB = (blockIdx.x * 4) >> 8;          // same b for the 4 units
  wr_s[tid] = wred[tid];
  hd_s[tid] = hds[bB * Ssz + tid];
  __syncthreads();
  const int t  = tid & 127;
  const int jh = tid >> 7;
  const float base  = tanhf(bcomp[t]);
  const float bred0 = bred[0];
  #pragma unroll 1
  for (int r = 0; r < 4; ++r) {
    const int u = blockIdx.x * 4 + r;
    const int i = u & 255;
    float swr = 0.f, accv = 0.f;
    #pragma unroll 1
    for (int jj = 0; jj < 128; ++jj) {
      const int j = jh * 128 + jj;
      const float w = wr_s[j];
      swr += w;
      if (hd_s[j] == i)
        accv += w * (spc[((size_t)bB * Ssz + j) * 128 + t] - base);
    }
    cAcc[jh][t] = accv;
    cSwr[jh][t] = swr;
    __syncthreads();
    if (jh == 0)
      out[((size_t)bB * Ssz + i) * 128 + t] =
          base * (cSwr[0][t] + cSwr[1][t]) + bred0 + cAcc[0][t] + cAcc[1][t];
    __syncthreads();
  }
}

extern "C" void kernel_launch(void* const* d_in, const int* in_sizes, int n_in,
                              void* d_out, int out_size, void* d_ws, size_t ws_size,
                              hipStream_t stream) {
  const float* tok   = (const float*)d_in[0];
  const float* dep   = (const float*)d_in[1];
  const int*   hds   = (const int*)  d_in[2];
  const float* Wdep  = (const float*)d_in[3];
  const float* bdep  = (const float*)d_in[4];
  const float* Wcomp = (const float*)d_in[5];
  const float* bcomp = (const float*)d_in[6];
  const float* Wred  = (const float*)d_in[7];
  const float* bred  = (const float*)d_in[8];
  float* out = (float*)d_out;

  char* ws = (char*)d_ws;
  _Float16* W1pk = (_Float16*)(ws);                 // 2 MB
  _Float16* W2pk = (_Float16*)(ws + (2u  << 20));   // 4 MB
  _Float16* dpk  = (_Float16*)(ws + (6u  << 20));   // 256 KB
  _Float16* tokT = (_Float16*)(ws + (7u  << 20));   // 512 KB
  _Float16* hpk  = (_Float16*)(ws + (8u  << 20));   // 512 KB
  float*    part = (float*)   (ws + (9u  << 20));   // 16 MB
  float*    spc  = (float*)   (ws + (25u << 20));   // 1 MB

  k_mega<<<dim3(NBLK), dim3(256), 0, stream>>>(
      tok, dep, hds, Wdep, bdep, Wcomp, bcomp, Wred, bred, out,
      W1pk, W2pk, dpk, tokT, hpk, part, spc);
}